// Round 11
// baseline (538.515 us; speedup 1.0000x reference)
//
#include <hip/hip_runtime.h>

#define CN 256
#define HN 64
#define WN 64
#define NNW 32
#define HW (HN*WN)            // 4096
#define NREF (NNW*HW)         // 131072
#define KD 256

#define BMT 256               // block M tile
#define BNT 128               // B rows per tile
#define NCHV 16               // n-chunks -> grid 256 = 1 block/CU
#define NTILES (NREF/NCHV/BNT) // 64

using bf16x8 = __attribute__((ext_vector_type(8))) short;
using f32x16 = __attribute__((ext_vector_type(16))) float;

__device__ inline unsigned short f2bf(float x) {
  unsigned int u = __float_as_uint(x);
  return (unsigned short)((u + 0x7fffu + ((u >> 16) & 1u)) >> 16);
}

__device__ inline void atomicMaxFloat(float* addr, float val) {
  if (val >= 0.f) atomicMax(reinterpret_cast<int*>(addr), __float_as_int(val));
  else            atomicMin(reinterpret_cast<unsigned int*>(addr), __float_as_uint(val));
}

__device__ inline void gload_lds16(const void* g, void* l) {
  __builtin_amdgcn_global_load_lds(
      (const __attribute__((address_space(1))) void*)g,
      (__attribute__((address_space(3))) void*)l, 16, 0, 0);
}

// ---------------- normalize (refs blocks 0..2047, img blocks 2048..2111) ----
__global__ __launch_bounds__(256)
void norm_kernel(const float* __restrict__ refs, const float* __restrict__ img,
                 unsigned short* __restrict__ Rb, unsigned short* __restrict__ Qb,
                 float* __restrict__ out) {
  __shared__ float tile[CN][WN + 1];
  __shared__ float ssq[4][WN];
  __shared__ float scl[WN];
  const int bid = blockIdx.x;
  const int t = threadIdx.x;
  const float* src; unsigned short* dst; int nh;
  if (bid < NNW * HN) { src = refs; dst = Rb; nh = bid; }
  else {
    src = img; dst = Qb; nh = bid - NNW * HN;
    if (t < 64) out[(size_t)nh * 64 + t] = -INFINITY;   // init output
  }
  const float* base = src + (size_t)(nh >> 6) * (CN * (size_t)HW) + (size_t)(nh & 63) * WN;

  const int c16 = t >> 4, w4 = (t & 15) * 4;
#pragma unroll
  for (int j = 0; j < 16; ++j) {
    int c = j * 16 + c16;
    float4 v = *(const float4*)&base[(size_t)c * HW + w4];
    tile[c][w4 + 0] = v.x; tile[c][w4 + 1] = v.y;
    tile[c][w4 + 2] = v.z; tile[c][w4 + 3] = v.w;
  }
  __syncthreads();
  {
    int w = t & 63, vv = t >> 6;
    float s = 0.f;
#pragma unroll 8
    for (int cc = 0; cc < 64; ++cc) { float x = tile[vv * 64 + cc][w]; s += x * x; }
    ssq[vv][w] = s;
  }
  __syncthreads();
  if (t < 64)
    scl[t] = 1.f / fmaxf(sqrtf(ssq[0][t] + ssq[1][t] + ssq[2][t] + ssq[3][t]), 1e-12f);
  __syncthreads();
  const int w = t >> 2, cq = t & 3;
  unsigned short* orow = dst + ((size_t)nh * WN + w) * KD;
  const float sc = scl[w];
#pragma unroll
  for (int j = 0; j < 8; ++j) {
    int c0 = (j * 4 + cq) * 8;
    bf16x8 o;
#pragma unroll
    for (int k = 0; k < 8; ++k) o[k] = (short)f2bf(tile[c0 + k][w] * sc);
    *(bf16x8*)&orow[c0] = o;
  }
}

// -- GEMM-max: 32x32x16 MFMA, XOR-32 row-major layout, A in regs, dbuf B -----
#define BARR() __builtin_amdgcn_s_barrier()
#define SCHED0() __builtin_amdgcn_sched_barrier(0)
#define GATE(N) asm volatile("s_waitcnt vmcnt(" #N ")" ::: "memory")
#define LGKM0() asm volatile("s_waitcnt lgkmcnt(0)" ::: "memory")

// one ni-strip: full K=256 in 2 halves; fresh acc chains; fold into run
#define STRIPNI(PB) do { \
  bf16x8 bb[8]; \
  f32x16 acc0, acc1; \
  _Pragma("unroll") \
  for (int kq = 0; kq < 8; ++kq) bb[kq] = *(const bf16x8*)&(PB)[(kq << 4) ^ hx8]; \
  __builtin_amdgcn_s_setprio(1); \
  _Pragma("unroll") \
  for (int kq = 0; kq < 8; ++kq) { \
    acc0 = __builtin_amdgcn_mfma_f32_32x32x16_bf16(a[0][kq], bb[kq], kq ? acc0 : ZZ, 0, 0, 0); \
    acc1 = __builtin_amdgcn_mfma_f32_32x32x16_bf16(a[1][kq], bb[kq], kq ? acc1 : ZZ, 0, 0, 0); \
  } \
  __builtin_amdgcn_s_setprio(0); \
  _Pragma("unroll") \
  for (int kq = 0; kq < 8; ++kq) bb[kq] = *(const bf16x8*)&(PB)[((8 + kq) << 4) ^ hx8]; \
  __builtin_amdgcn_s_setprio(1); \
  _Pragma("unroll") \
  for (int kq = 0; kq < 8; ++kq) { \
    acc0 = __builtin_amdgcn_mfma_f32_32x32x16_bf16(a[0][8 + kq], bb[kq], acc0, 0, 0, 0); \
    acc1 = __builtin_amdgcn_mfma_f32_32x32x16_bf16(a[1][8 + kq], bb[kq], acc1, 0, 0, 0); \
  } \
  __builtin_amdgcn_s_setprio(0); \
  _Pragma("unroll") \
  for (int e = 0; e < 16; ++e) { \
    run0[e] = fmaxf(run0[e], acc0[e]); \
    run1[e] = fmaxf(run1[e], acc1[e]); \
  } \
} while (0)

__global__ __launch_bounds__(512, 1)
void simmax_kernel(const unsigned short* __restrict__ Q,
                   const unsigned short* __restrict__ R,
                   float* __restrict__ out) {
  // 2 bufs x [128 rows][32 chunks x 16B]; phys chunk = logical ^ (row&31). 128 KB.
  __shared__ unsigned short lds[2][32768];

  const int t = threadIdx.x;
  const int lane = t & 63;
  const int wid = t >> 6;       // 0..7
  const int wm = wid >> 1;      // 0..3 (M)
  const int wn = wid & 1;       // 0..1 (N)
  const int hi31 = lane >> 5;   // 0/1
  const int l31 = lane & 31;

  // bijective XCD swizzle: XCD x hosts wg [x*32, x*32+32) = 2 nch x 16 bm
  const int wg  = (blockIdx.x & 7) * 32 + (blockIdx.x >> 3);
  const int nch = wg >> 4;      // 0..15
  const int bm  = wg & 15;      // 0..15

  // B staging source offsets (shorts): q covers rows wid*16+q*2+{0,1}
  int boff[8];
#pragma unroll
  for (int q = 0; q < 8; ++q) {
    int row = wid * 16 + q * 2 + hi31;
    boff[q] = row * 256 + (l31 ^ (row & 31)) * 8;
  }
  const unsigned short* rbase = R + (size_t)nch * ((size_t)NTILES * BNT) * KD;
  const unsigned short* qbase = Q + (size_t)bm * BMT * KD;

  // ---- A prologue: 256 rows x 256 k staged XOR-32 across both bufs ----
#pragma unroll
  for (int p = 0; p < 16; ++p) {
    int row = wid * 32 + p * 2 + hi31;
    gload_lds16(qbase + row * 256 + (l31 ^ (row & 31)) * 8,
                &lds[wid >> 2][((wid & 3) * 32 + p * 2) * 256]);
  }
  GATE(0); BARR(); SCHED0();

  const int hx8 = (hi31 ^ l31) * 8;
  bf16x8 a[2][16];              // resident A: 2 m-frags(32 rows) x 16 k-frags
#pragma unroll
  for (int mi = 0; mi < 2; ++mi) {
    const int mrow = wm * 64 + mi * 32 + l31;
    const unsigned short* pa = &lds[mrow >> 7][(mrow & 127) * 256];
#pragma unroll
    for (int kf = 0; kf < 16; ++kf)
      a[mi][kf] = *(const bf16x8*)&pa[(kf << 4) ^ hx8];
  }
  LGKM0(); BARR();              // all waves done reading A before B overwrites

  const f32x16 ZZ = {0,0,0,0,0,0,0,0,0,0,0,0,0,0,0,0};
  f32x16 run0, run1;
#pragma unroll
  for (int e = 0; e < 16; ++e) { run0[e] = -1e30f; run1[e] = -1e30f; }

  // ---- B tiles: double-buffered; stage next, GATE(8), BARR, strips, BARR
  const unsigned short* rs = rbase;
#pragma unroll
  for (int q = 0; q < 8; ++q)
    gload_lds16(rs + boff[q], &lds[0][(wid * 8 + q) * 512]);

  for (int bt = 0; bt < NTILES - 1; ++bt) {
    const unsigned short* rsn = rs + 32768;
    unsigned short* dst = &lds[(bt + 1) & 1][0];
#pragma unroll
    for (int q = 0; q < 8; ++q)
      gload_lds16(rsn + boff[q], dst + (wid * 8 + q) * 512);
    GATE(8); BARR(); SCHED0();
    const unsigned short* pb = &lds[bt & 1][(wn * 64 + l31) * 256];
    STRIPNI(pb);
    STRIPNI(pb + 8192);         // ni=1: +32 rows
    BARR();
    rs = rsn;
  }
  GATE(0); BARR(); SCHED0();
  {
    const unsigned short* pb = &lds[(NTILES - 1) & 1][(wn * 64 + l31) * 256];
    STRIPNI(pb);
    STRIPNI(pb + 8192);
  }

  // reduce over the 32 column-lanes, one atomic per output row
#pragma unroll
  for (int mi = 0; mi < 2; ++mi)
#pragma unroll
    for (int e = 0; e < 16; ++e) {
      float v = mi ? run1[e] : run0[e];
      v = fmaxf(v, __shfl_xor(v, 1));
      v = fmaxf(v, __shfl_xor(v, 2));
      v = fmaxf(v, __shfl_xor(v, 4));
      v = fmaxf(v, __shfl_xor(v, 8));
      v = fmaxf(v, __shfl_xor(v, 16));
      if (l31 == 0) {
        int row = bm * BMT + wm * 64 + mi * 32 + (e & 3) + 8 * (e >> 2) + 4 * hi31;
        atomicMaxFloat(&out[row], v);
      }
    }
}

extern "C" void kernel_launch(void* const* d_in, const int* in_sizes, int n_in,
                              void* d_out, int out_size, void* d_ws, size_t ws_size,
                              hipStream_t stream) {
  const float* refs = (const float*)d_in[0];
  const float* img  = (const float*)d_in[1];
  float* out = (float*)d_out;

  unsigned short* Rb = (unsigned short*)d_ws;                 // 131072*256 bf16 = 64MB
  unsigned short* Qb = Rb + (size_t)NREF * KD;                // 4096*256 bf16 = 2MB

  hipLaunchKernelGGL(norm_kernel, dim3(NNW * HN + HN), dim3(256), 0, stream,
                     refs, img, Rb, Qb, out);
  hipLaunchKernelGGL(simmax_kernel, dim3(NCHV * (HW / BMT)), dim3(512), 0, stream,
                     Qb, Rb, out);
}

// Round 12
// 251.714 us; speedup vs baseline: 2.1394x; 2.1394x over previous
//
#include <hip/hip_runtime.h>

#define CN 256
#define HN 64
#define WN 64
#define NNW 32
#define HW (HN*WN)            // 4096
#define NREF (NNW*HW)         // 131072
#define KD 256

#define BMT 128               // block M tile
#define BNT 64                // B rows per tile (32 KB)
#define NCHV 16               // n-chunks; grid = 32 bm x 16 nch = 512 = 2/CU
#define NTILES (NREF/NCHV/BNT) // 128

using bf16x8 = __attribute__((ext_vector_type(8))) short;
using f32x4  = __attribute__((ext_vector_type(4))) float;

__device__ inline unsigned short f2bf(float x) {
  unsigned int u = __float_as_uint(x);
  return (unsigned short)((u + 0x7fffu + ((u >> 16) & 1u)) >> 16);
}

__device__ inline void atomicMaxFloat(float* addr, float val) {
  if (val >= 0.f) atomicMax(reinterpret_cast<int*>(addr), __float_as_int(val));
  else            atomicMin(reinterpret_cast<unsigned int*>(addr), __float_as_uint(val));
}

__device__ inline void gload_lds16(const void* g, void* l) {
  __builtin_amdgcn_global_load_lds(
      (const __attribute__((address_space(1))) void*)g,
      (__attribute__((address_space(3))) void*)l, 16, 0, 0);
}

// ---------------- normalize (refs blocks 0..2047, img blocks 2048..2111) ----
__global__ __launch_bounds__(256)
void norm_kernel(const float* __restrict__ refs, const float* __restrict__ img,
                 unsigned short* __restrict__ Rb, unsigned short* __restrict__ Qb,
                 float* __restrict__ out) {
  __shared__ float tile[CN][WN + 1];
  __shared__ float ssq[4][WN];
  __shared__ float scl[WN];
  const int bid = blockIdx.x;
  const int t = threadIdx.x;
  const float* src; unsigned short* dst; int nh;
  if (bid < NNW * HN) { src = refs; dst = Rb; nh = bid; }
  else {
    src = img; dst = Qb; nh = bid - NNW * HN;
    if (t < 64) out[(size_t)nh * 64 + t] = -INFINITY;   // init output
  }
  const float* base = src + (size_t)(nh >> 6) * (CN * (size_t)HW) + (size_t)(nh & 63) * WN;

  const int c16 = t >> 4, w4 = (t & 15) * 4;
#pragma unroll
  for (int j = 0; j < 16; ++j) {
    int c = j * 16 + c16;
    float4 v = *(const float4*)&base[(size_t)c * HW + w4];
    tile[c][w4 + 0] = v.x; tile[c][w4 + 1] = v.y;
    tile[c][w4 + 2] = v.z; tile[c][w4 + 3] = v.w;
  }
  __syncthreads();
  {
    int w = t & 63, vv = t >> 6;
    float s = 0.f;
#pragma unroll 8
    for (int cc = 0; cc < 64; ++cc) { float x = tile[vv * 64 + cc][w]; s += x * x; }
    ssq[vv][w] = s;
  }
  __syncthreads();
  if (t < 64)
    scl[t] = 1.f / fmaxf(sqrtf(ssq[0][t] + ssq[1][t] + ssq[2][t] + ssq[3][t]), 1e-12f);
  __syncthreads();
  const int w = t >> 2, cq = t & 3;
  unsigned short* orow = dst + ((size_t)nh * WN + w) * KD;
  const float sc = scl[w];
#pragma unroll
  for (int j = 0; j < 8; ++j) {
    int c0 = (j * 4 + cq) * 8;
    bf16x8 o;
#pragma unroll
    for (int k = 0; k < 8; ++k) o[k] = (short)f2bf(tile[c0 + k][w] * sc);
    *(bf16x8*)&orow[c0] = o;
  }
}

// -- GEMM-max: 4 waves, A in regs, 32KB full-K B tiles dbuf, 2 blocks/CU -----
#define BARR() __builtin_amdgcn_s_barrier()
#define SCHED0() __builtin_amdgcn_sched_barrier(0)
#define GATE(N) asm volatile("s_waitcnt vmcnt(" #N ")" ::: "memory")
#define LGKM0() asm volatile("s_waitcnt lgkmcnt(0)" ::: "memory")

// stage one B tile (64 rows x 256 k = 32KB) into buf P: wave wid covers
// k-quarter wid (sub wid); 8 gloads/thread, gload q = rows q*8..q*8+8
#define STGB(P, BT) do { \
  _Pragma("unroll") \
  for (int q = 0; q < 8; ++q) \
    gload_lds16(rsb + (BT) * 16384 + q * 2048, &lds[P][wid * 4096 + q * 512]); \
} while (0)

// one ni-strip (16 refs x full K=256): 8 b128 reads + 2 independent 8-chains
#define STRIP(P, NI) do { \
  bf16x8 bb[8]; \
  _Pragma("unroll") \
  for (int kf = 0; kf < 8; ++kf) \
    bb[kf] = *(const bf16x8*)&lds[P][(kf >> 1) * 4096 + ((NI) * 16 + l15) * 64 \
        + ((((kf & 1) * 4 + (lane >> 4)) ^ l7) * 8)]; \
  f32x4 acc0, acc1; \
  __builtin_amdgcn_s_setprio(1); \
  _Pragma("unroll") \
  for (int kf = 0; kf < 8; ++kf) { \
    acc0 = __builtin_amdgcn_mfma_f32_16x16x32_bf16(a[0][kf], bb[kf], kf ? acc0 : ZZ, 0, 0, 0); \
    acc1 = __builtin_amdgcn_mfma_f32_16x16x32_bf16(a[1][kf], bb[kf], kf ? acc1 : ZZ, 0, 0, 0); \
  } \
  __builtin_amdgcn_s_setprio(0); \
  _Pragma("unroll") \
  for (int ee = 0; ee < 4; ++ee) { \
    run0[ee] = fmaxf(run0[ee], acc0[ee]); \
    run1[ee] = fmaxf(run1[ee], acc1[ee]); \
  } \
} while (0)

#define STRIPS(P) do { STRIP(P, 0); STRIP(P, 1); STRIP(P, 2); STRIP(P, 3); } while (0)

__global__ __launch_bounds__(256, 2)
void simmax_kernel(const unsigned short* __restrict__ Q,
                   const unsigned short* __restrict__ R,
                   float* __restrict__ out) {
  // 2 bufs x 4 subs of [64 rows][64 k] bf16 (8 KB each). 64 KB -> 2 blocks/CU.
  __shared__ unsigned short lds[2][16384];

  const int t = threadIdx.x;
  const int lane = t & 63;
  const int wid = t >> 6;       // 0..3 (M-slot, 32 rows each)
  const int l15 = lane & 15;
  const int l7  = lane & 7;

  // bijective XCD swizzle: XCD x hosts wg [x*64, x*64+64) = 2 nch x 32 bm
  const int wg  = (blockIdx.x & 7) * 64 + (blockIdx.x >> 3);
  const int nch = wg >> 5;      // 0..15
  const int bm  = wg & 31;      // 0..31

  // staging: row-in-8 = lane>>3, phys chunk lane&7, src chunk = (lane&7)^(lane>>3)
  const int srow = lane >> 3;
  const int schunk = (lane & 7) ^ srow;
  // B source for wave wid (k-quarter wid), tile-row srow
  const unsigned short* rsb = R + ((size_t)nch * 8192 + srow) * KD + wid * 64 + schunk * 8;

  const f32x4 ZZ = {0.f, 0.f, 0.f, 0.f};
  f32x4 run0, run1;
#pragma unroll
  for (int ee = 0; ee < 4; ++ee) { run0[ee] = -1e30f; run1[ee] = -1e30f; }

  // ---- A prologue: 128 rows x 256 k = 64 KB across both bufs; read to regs
#pragma unroll
  for (int b = 0; b < 2; ++b) {
    const unsigned short* qsb = Q + (size_t)(bm * BMT + b * 64 + srow) * KD
                                  + wid * 64 + schunk * 8;
#pragma unroll
    for (int q = 0; q < 8; ++q)
      gload_lds16(qsb + q * 2048, &lds[b][wid * 4096 + q * 512]);
  }
  GATE(0); BARR(); SCHED0();

  bf16x8 a[2][8];               // resident A: 2 m-frags x 8 k-frags = 64 VGPR
#pragma unroll
  for (int mi = 0; mi < 2; ++mi) {
    const int row = wid * 32 + mi * 16 + l15;      // [wid*32, wid*32+32)
    const int r63 = row & 63;
#pragma unroll
    for (int kf = 0; kf < 8; ++kf)
      a[mi][kf] = *(const bf16x8*)&lds[wid >> 1][(kf >> 1) * 4096 + r63 * 64
          + ((((kf & 1) * 4 + (lane >> 4)) ^ l7) * 8)];
  }
  LGKM0(); BARR();              // all waves done reading A before B overwrites

  // ---- B tiles: dbuf; stage next, GATE(8), BARR, strips, BARR
  STGB(0, 0);
  for (int bt = 0; bt < NTILES - 1; ++bt) {
    STGB((bt + 1) & 1, bt + 1);
    GATE(8); BARR(); SCHED0();
    STRIPS(bt & 1);
    BARR();
  }
  GATE(0); BARR(); SCHED0();
  STRIPS((NTILES - 1) & 1);

  // reduce over the 16 column-lanes, one atomic per output row
#pragma unroll
  for (int mi = 0; mi < 2; ++mi)
#pragma unroll
    for (int ee = 0; ee < 4; ++ee) {
      float v = mi ? run1[ee] : run0[ee];
      v = fmaxf(v, __shfl_xor(v, 1));
      v = fmaxf(v, __shfl_xor(v, 2));
      v = fmaxf(v, __shfl_xor(v, 4));
      v = fmaxf(v, __shfl_xor(v, 8));
      if (l15 == 0)
        atomicMaxFloat(&out[bm * BMT + wid * 32 + mi * 16 + (lane >> 4) * 4 + ee], v);
    }
}

extern "C" void kernel_launch(void* const* d_in, const int* in_sizes, int n_in,
                              void* d_out, int out_size, void* d_ws, size_t ws_size,
                              hipStream_t stream) {
  const float* refs = (const float*)d_in[0];
  const float* img  = (const float*)d_in[1];
  float* out = (float*)d_out;

  unsigned short* Rb = (unsigned short*)d_ws;                 // 131072*256 bf16 = 64MB
  unsigned short* Qb = Rb + (size_t)NREF * KD;                // 4096*256 bf16 = 2MB

  hipLaunchKernelGGL(norm_kernel, dim3(NNW * HN + HN), dim3(256), 0, stream,
                     refs, img, Rb, Qb, out);
  hipLaunchKernelGGL(simmax_kernel, dim3(NCHV * (HW / BMT)), dim3(256), 0, stream,
                     Qb, Rb, out);
}

// Round 13
// 216.595 us; speedup vs baseline: 2.4863x; 1.1621x over previous
//
#include <hip/hip_runtime.h>

#define CN 256
#define HN 64
#define WN 64
#define NNW 32
#define HW (HN*WN)            // 4096
#define NREF (NNW*HW)         // 131072
#define KD 256

#define BMT 256               // block M tile (wave owns 64 rows)
#define BNT 64                // B rows per tile (32 KB, full K)
#define NCHV 32               // n-chunks; grid = 16 bm x 32 nch = 512 = 2/CU
#define NTILES (NREF/NCHV/BNT) // 64

using bf16x8 = __attribute__((ext_vector_type(8))) short;
using f32x4  = __attribute__((ext_vector_type(4))) float;

__device__ inline unsigned short f2bf(float x) {
  unsigned int u = __float_as_uint(x);
  return (unsigned short)((u + 0x7fffu + ((u >> 16) & 1u)) >> 16);
}

__device__ inline void atomicMaxFloat(float* addr, float val) {
  if (val >= 0.f) atomicMax(reinterpret_cast<int*>(addr), __float_as_int(val));
  else            atomicMin(reinterpret_cast<unsigned int*>(addr), __float_as_uint(val));
}

__device__ inline void gload_lds16(const void* g, void* l) {
  __builtin_amdgcn_global_load_lds(
      (const __attribute__((address_space(1))) void*)g,
      (__attribute__((address_space(3))) void*)l, 16, 0, 0);
}

// ---------------- normalize (refs blocks 0..2047, img blocks 2048..2111) ----
__global__ __launch_bounds__(256)
void norm_kernel(const float* __restrict__ refs, const float* __restrict__ img,
                 unsigned short* __restrict__ Rb, unsigned short* __restrict__ Qb,
                 float* __restrict__ out) {
  __shared__ float tile[CN][WN + 1];
  __shared__ float ssq[4][WN];
  __shared__ float scl[WN];
  const int bid = blockIdx.x;
  const int t = threadIdx.x;
  const float* src; unsigned short* dst; int nh;
  if (bid < NNW * HN) { src = refs; dst = Rb; nh = bid; }
  else {
    src = img; dst = Qb; nh = bid - NNW * HN;
    if (t < 64) out[(size_t)nh * 64 + t] = -INFINITY;   // init output
  }
  const float* base = src + (size_t)(nh >> 6) * (CN * (size_t)HW) + (size_t)(nh & 63) * WN;

  const int c16 = t >> 4, w4 = (t & 15) * 4;
#pragma unroll
  for (int j = 0; j < 16; ++j) {
    int c = j * 16 + c16;
    float4 v = *(const float4*)&base[(size_t)c * HW + w4];
    tile[c][w4 + 0] = v.x; tile[c][w4 + 1] = v.y;
    tile[c][w4 + 2] = v.z; tile[c][w4 + 3] = v.w;
  }
  __syncthreads();
  {
    int w = t & 63, vv = t >> 6;
    float s = 0.f;
#pragma unroll 8
    for (int cc = 0; cc < 64; ++cc) { float x = tile[vv * 64 + cc][w]; s += x * x; }
    ssq[vv][w] = s;
  }
  __syncthreads();
  if (t < 64)
    scl[t] = 1.f / fmaxf(sqrtf(ssq[0][t] + ssq[1][t] + ssq[2][t] + ssq[3][t]), 1e-12f);
  __syncthreads();
  const int w = t >> 2, cq = t & 3;
  unsigned short* orow = dst + ((size_t)nh * WN + w) * KD;
  const float sc = scl[w];
#pragma unroll
  for (int j = 0; j < 8; ++j) {
    int c0 = (j * 4 + cq) * 8;
    bf16x8 o;
#pragma unroll
    for (int k = 0; k < 8; ++k) o[k] = (short)f2bf(tile[c0 + k][w] * sc);
    *(bf16x8*)&orow[c0] = o;
  }
}

// -- GEMM-max: 4 waves x 64 M-rows in regs, 32KB B tiles dbuf, 2 blocks/CU ---
#define BARR() __builtin_amdgcn_s_barrier()
#define SCHED0() __builtin_amdgcn_sched_barrier(0)
#define GATE(N) asm volatile("s_waitcnt vmcnt(" #N ")" ::: "memory")
#define LGKM0() asm volatile("s_waitcnt lgkmcnt(0)" ::: "memory")

// stage one B tile (64 rows x 256 k = 32KB) into buf P: wave wid stages
// k-quarter wid; 8 gloads/thread, gload q covers rows q*8..q*8+8
#define STGB(P, BT) do { \
  _Pragma("unroll") \
  for (int q = 0; q < 8; ++q) \
    gload_lds16(rsb + (BT) * 16384 + q * 2048, &lds[P][wid * 4096 + q * 512]); \
} while (0)

// one ni-strip (16 refs x full K=256): 8 b128 reads amortized over 4 m-frags
#define STRIP(P, NI) do { \
  bf16x8 bb[8]; \
  _Pragma("unroll") \
  for (int kf = 0; kf < 8; ++kf) \
    bb[kf] = *(const bf16x8*)&lds[P][(kf >> 1) * 4096 + ((NI) * 16 + l15) * 64 \
        + ((((kf & 1) * 4 + (lane >> 4)) ^ l7) * 8)]; \
  f32x4 ac0, ac1, ac2, ac3; \
  __builtin_amdgcn_s_setprio(1); \
  _Pragma("unroll") \
  for (int kf = 0; kf < 8; ++kf) { \
    ac0 = __builtin_amdgcn_mfma_f32_16x16x32_bf16(a[0][kf], bb[kf], kf ? ac0 : ZZ, 0, 0, 0); \
    ac1 = __builtin_amdgcn_mfma_f32_16x16x32_bf16(a[1][kf], bb[kf], kf ? ac1 : ZZ, 0, 0, 0); \
    ac2 = __builtin_amdgcn_mfma_f32_16x16x32_bf16(a[2][kf], bb[kf], kf ? ac2 : ZZ, 0, 0, 0); \
    ac3 = __builtin_amdgcn_mfma_f32_16x16x32_bf16(a[3][kf], bb[kf], kf ? ac3 : ZZ, 0, 0, 0); \
  } \
  __builtin_amdgcn_s_setprio(0); \
  _Pragma("unroll") \
  for (int ee = 0; ee < 4; ++ee) { \
    run[0][ee] = fmaxf(run[0][ee], ac0[ee]); \
    run[1][ee] = fmaxf(run[1][ee], ac1[ee]); \
    run[2][ee] = fmaxf(run[2][ee], ac2[ee]); \
    run[3][ee] = fmaxf(run[3][ee], ac3[ee]); \
  } \
} while (0)

#define STRIPS(P) do { STRIP(P, 0); STRIP(P, 1); STRIP(P, 2); STRIP(P, 3); } while (0)

__global__ __launch_bounds__(256, 2)
void simmax_kernel(const unsigned short* __restrict__ Q,
                   const unsigned short* __restrict__ R,
                   float* __restrict__ out) {
  // 2 bufs x 4 subs of [64 rows][64 k] bf16 (8 KB each). 64 KB -> 2 blocks/CU.
  __shared__ unsigned short lds[2][16384];

  const int t = threadIdx.x;
  const int lane = t & 63;
  const int wid = t >> 6;       // 0..3 (owns M rows [wid*64, wid*64+64))
  const int l15 = lane & 15;
  const int l7  = lane & 7;

  // bijective XCD swizzle: XCD x hosts wg [x*64, x*64+64)
  const int wg  = (blockIdx.x & 7) * 64 + (blockIdx.x >> 3);
  const int nch = wg >> 4;      // 0..31
  const int bm  = wg & 15;      // 0..15

  // staging: row-in-8 = lane>>3, phys chunk lane&7, src chunk = (lane&7)^(lane>>3)
  const int srow = lane >> 3;
  const int schunk = (lane & 7) ^ srow;
  // B source for wave wid (k-quarter wid), tile-row srow
  const unsigned short* rsb = R + ((size_t)nch * 4096 + srow) * KD + wid * 64 + schunk * 8;

  const f32x4 ZZ = {0.f, 0.f, 0.f, 0.f};
  f32x4 run[4];
#pragma unroll
  for (int mi = 0; mi < 4; ++mi)
#pragma unroll
    for (int ee = 0; ee < 4; ++ee) run[mi][ee] = -1e30f;

  // ---- A prologue: 256 rows x 256 k in 2 passes of 128 rows (64 KB each)
  bf16x8 a[4][8];               // resident A: 4 m-frags x 8 k-frags = 128 VGPR
#pragma unroll
  for (int p = 0; p < 2; ++p) {
#pragma unroll
    for (int b = 0; b < 2; ++b) {
      const unsigned short* qsb = Q + (size_t)(bm * BMT + p * 128 + b * 64 + srow) * KD
                                    + wid * 64 + schunk * 8;
#pragma unroll
      for (int q = 0; q < 8; ++q)
        gload_lds16(qsb + q * 2048, &lds[b][wid * 4096 + q * 512]);
    }
    GATE(0); BARR(); SCHED0();
    if ((wid >> 1) == p) {      // waves whose 64 M-rows live in this pass
      const int b = wid & 1;
#pragma unroll
      for (int mi = 0; mi < 4; ++mi)
#pragma unroll
        for (int kf = 0; kf < 8; ++kf)
          a[mi][kf] = *(const bf16x8*)&lds[b][(kf >> 1) * 4096 + (mi * 16 + l15) * 64
              + ((((kf & 1) * 4 + (lane >> 4)) ^ l7) * 8)];
    }
    LGKM0(); BARR();            // reads done before next pass / B overwrites
  }

  // ---- B tiles: dbuf; stage next, GATE(8), BARR, strips, BARR
  STGB(0, 0);
  for (int bt = 0; bt < NTILES - 1; ++bt) {
    STGB((bt + 1) & 1, bt + 1);
    GATE(8); BARR(); SCHED0();
    STRIPS(bt & 1);
    BARR();
  }
  GATE(0); BARR(); SCHED0();
  STRIPS((NTILES - 1) & 1);

  // reduce over the 16 column-lanes, one atomic per output row
#pragma unroll
  for (int mi = 0; mi < 4; ++mi)
#pragma unroll
    for (int ee = 0; ee < 4; ++ee) {
      float v = run[mi][ee];
      v = fmaxf(v, __shfl_xor(v, 1));
      v = fmaxf(v, __shfl_xor(v, 2));
      v = fmaxf(v, __shfl_xor(v, 4));
      v = fmaxf(v, __shfl_xor(v, 8));
      if (l15 == 0)
        atomicMaxFloat(&out[bm * BMT + wid * 64 + mi * 16 + (lane >> 4) * 4 + ee], v);
    }
}

extern "C" void kernel_launch(void* const* d_in, const int* in_sizes, int n_in,
                              void* d_out, int out_size, void* d_ws, size_t ws_size,
                              hipStream_t stream) {
  const float* refs = (const float*)d_in[0];
  const float* img  = (const float*)d_in[1];
  float* out = (float*)d_out;

  unsigned short* Rb = (unsigned short*)d_ws;                 // 131072*256 bf16 = 64MB
  unsigned short* Qb = Rb + (size_t)NREF * KD;                // 4096*256 bf16 = 2MB

  hipLaunchKernelGGL(norm_kernel, dim3(NNW * HN + HN), dim3(256), 0, stream,
                     refs, img, Rb, Qb, out);
  hipLaunchKernelGGL(simmax_kernel, dim3(NCHV * (HW / BMT)), dim3(256), 0, stream,
                     Qb, Rb, out);
}

// Round 14
// 215.594 us; speedup vs baseline: 2.4978x; 1.0046x over previous
//
#include <hip/hip_runtime.h>

#define CN 256
#define HN 64
#define WN 64
#define NNW 32
#define HW (HN*WN)            // 4096
#define NREF (NNW*HW)         // 131072
#define KD 256

#define BMT 256               // block M tile (wave owns 64 rows)
#define BNT 64                // B rows per tile (32 KB, full K)
#define NCHV 32               // n-chunks; grid = 16 bm x 32 nch = 512 = 2/CU
#define NTILES (NREF/NCHV/BNT) // 64

using bf16x8 = __attribute__((ext_vector_type(8))) short;
using f32x4  = __attribute__((ext_vector_type(4))) float;

__device__ inline unsigned short f2bf(float x) {
  unsigned int u = __float_as_uint(x);
  return (unsigned short)((u + 0x7fffu + ((u >> 16) & 1u)) >> 16);
}

__device__ inline void atomicMaxFloat(float* addr, float val) {
  if (val >= 0.f) atomicMax(reinterpret_cast<int*>(addr), __float_as_int(val));
  else            atomicMin(reinterpret_cast<unsigned int*>(addr), __float_as_uint(val));
}

__device__ inline void gload_lds16(const void* g, void* l) {
  __builtin_amdgcn_global_load_lds(
      (const __attribute__((address_space(1))) void*)g,
      (__attribute__((address_space(3))) void*)l, 16, 0, 0);
}

// ---------------- normalize (refs blocks 0..2047, img blocks 2048..2111) ----
__global__ __launch_bounds__(256)
void norm_kernel(const float* __restrict__ refs, const float* __restrict__ img,
                 unsigned short* __restrict__ Rb, unsigned short* __restrict__ Qb,
                 float* __restrict__ out) {
  __shared__ float tile[CN][WN + 1];
  __shared__ float ssq[4][WN];
  __shared__ float scl[WN];
  const int bid = blockIdx.x;
  const int t = threadIdx.x;
  const float* src; unsigned short* dst; int nh;
  if (bid < NNW * HN) { src = refs; dst = Rb; nh = bid; }
  else {
    src = img; dst = Qb; nh = bid - NNW * HN;
    if (t < 64) out[(size_t)nh * 64 + t] = -INFINITY;   // init output
  }
  const float* base = src + (size_t)(nh >> 6) * (CN * (size_t)HW) + (size_t)(nh & 63) * WN;

  const int c16 = t >> 4, w4 = (t & 15) * 4;
#pragma unroll
  for (int j = 0; j < 16; ++j) {
    int c = j * 16 + c16;
    float4 v = *(const float4*)&base[(size_t)c * HW + w4];
    tile[c][w4 + 0] = v.x; tile[c][w4 + 1] = v.y;
    tile[c][w4 + 2] = v.z; tile[c][w4 + 3] = v.w;
  }
  __syncthreads();
  {
    int w = t & 63, vv = t >> 6;
    float s = 0.f;
#pragma unroll 8
    for (int cc = 0; cc < 64; ++cc) { float x = tile[vv * 64 + cc][w]; s += x * x; }
    ssq[vv][w] = s;
  }
  __syncthreads();
  if (t < 64)
    scl[t] = 1.f / fmaxf(sqrtf(ssq[0][t] + ssq[1][t] + ssq[2][t] + ssq[3][t]), 1e-12f);
  __syncthreads();
  const int w = t >> 2, cq = t & 3;
  unsigned short* orow = dst + ((size_t)nh * WN + w) * KD;
  const float sc = scl[w];
#pragma unroll
  for (int j = 0; j < 8; ++j) {
    int c0 = (j * 4 + cq) * 8;
    bf16x8 o;
#pragma unroll
    for (int k = 0; k < 8; ++k) o[k] = (short)f2bf(tile[c0 + k][w] * sc);
    *(bf16x8*)&orow[c0] = o;
  }
}

// -- GEMM-max: 4 waves x 64 M-rows in regs, dbuf B tiles, bb-pipelined strips
#define BARR() __builtin_amdgcn_s_barrier()
#define SCHED0() __builtin_amdgcn_sched_barrier(0)
#define GATE(N) asm volatile("s_waitcnt vmcnt(" #N ")" ::: "memory")
#define LGKM0() asm volatile("s_waitcnt lgkmcnt(0)" ::: "memory")

// stage one B tile (64 rows x 256 k = 32KB) into buf P: wave wid stages
// k-quarter wid; 8 gloads/thread, gload q covers rows q*8..q*8+8
#define STGB(P, BT) do { \
  _Pragma("unroll") \
  for (int q = 0; q < 8; ++q) \
    gload_lds16(rsb + (BT) * 16384 + q * 2048, &lds[P][wid * 4096 + q * 512]); \
} while (0)

// read the 8 B-fragments of ni-strip NI into register set BB
#define RDB(P, NI, BB) do { \
  _Pragma("unroll") \
  for (int kf = 0; kf < 8; ++kf) \
    BB[kf] = *(const bf16x8*)&lds[P][(kf >> 1) * 4096 + ((NI) * 16 + l15) * 64 \
        + ((((kf & 1) * 4 + (lane >> 4)) ^ l7) * 8)]; \
} while (0)

// 32-MFMA chain on fragment set BB (4 m-frags), fold into run
#define MF4(BB) do { \
  f32x4 ac0, ac1, ac2, ac3; \
  __builtin_amdgcn_s_setprio(1); \
  _Pragma("unroll") \
  for (int kf = 0; kf < 8; ++kf) { \
    ac0 = __builtin_amdgcn_mfma_f32_16x16x32_bf16(a[0][kf], BB[kf], kf ? ac0 : ZZ, 0, 0, 0); \
    ac1 = __builtin_amdgcn_mfma_f32_16x16x32_bf16(a[1][kf], BB[kf], kf ? ac1 : ZZ, 0, 0, 0); \
    ac2 = __builtin_amdgcn_mfma_f32_16x16x32_bf16(a[2][kf], BB[kf], kf ? ac2 : ZZ, 0, 0, 0); \
    ac3 = __builtin_amdgcn_mfma_f32_16x16x32_bf16(a[3][kf], BB[kf], kf ? ac3 : ZZ, 0, 0, 0); \
  } \
  __builtin_amdgcn_s_setprio(0); \
  _Pragma("unroll") \
  for (int ee = 0; ee < 4; ++ee) { \
    run[0][ee] = fmaxf(run[0][ee], ac0[ee]); \
    run[1][ee] = fmaxf(run[1][ee], ac1[ee]); \
    run[2][ee] = fmaxf(run[2][ee], ac2[ee]); \
    run[3][ee] = fmaxf(run[3][ee], ac3[ee]); \
  } \
} while (0)

// one tile: bbA/bbB double-buffered strips -> next strip's reads overlap MFMA
#define TILE(P) do { \
  RDB(P, 0, bbA); \
  RDB(P, 1, bbB); MF4(bbA); \
  RDB(P, 2, bbA); MF4(bbB); \
  RDB(P, 3, bbB); MF4(bbA); \
  MF4(bbB); \
} while (0)

__global__ __launch_bounds__(256, 2)
void simmax_kernel(const unsigned short* __restrict__ Q,
                   const unsigned short* __restrict__ R,
                   float* __restrict__ out) {
  // 2 bufs x 4 subs of [64 rows][64 k] bf16 (8 KB each). 64 KB -> 2 blocks/CU.
  __shared__ unsigned short lds[2][16384];

  const int t = threadIdx.x;
  const int lane = t & 63;
  const int wid = t >> 6;       // 0..3 (owns M rows [wid*64, wid*64+64))
  const int l15 = lane & 15;
  const int l7  = lane & 7;

  // bijective XCD swizzle: XCD x hosts wg [x*64, x*64+64)
  const int wg  = (blockIdx.x & 7) * 64 + (blockIdx.x >> 3);
  const int nch = wg >> 4;      // 0..31
  const int bm  = wg & 15;      // 0..15

  // staging: row-in-8 = lane>>3, phys chunk lane&7, src chunk = (lane&7)^(lane>>3)
  const int srow = lane >> 3;
  const int schunk = (lane & 7) ^ srow;
  // B source for wave wid (k-quarter wid), tile-row srow
  const unsigned short* rsb = R + ((size_t)nch * 4096 + srow) * KD + wid * 64 + schunk * 8;

  const f32x4 ZZ = {0.f, 0.f, 0.f, 0.f};
  f32x4 run[4];
#pragma unroll
  for (int mi = 0; mi < 4; ++mi)
#pragma unroll
    for (int ee = 0; ee < 4; ++ee) run[mi][ee] = -1e30f;

  // ---- A prologue: 256 rows x 256 k in 2 passes of 128 rows (64 KB each)
  bf16x8 a[4][8];               // resident A: 4 m-frags x 8 k-frags = 128 VGPR
#pragma unroll
  for (int p = 0; p < 2; ++p) {
#pragma unroll
    for (int b = 0; b < 2; ++b) {
      const unsigned short* qsb = Q + (size_t)(bm * BMT + p * 128 + b * 64 + srow) * KD
                                    + wid * 64 + schunk * 8;
#pragma unroll
      for (int q = 0; q < 8; ++q)
        gload_lds16(qsb + q * 2048, &lds[b][wid * 4096 + q * 512]);
    }
    GATE(0); BARR(); SCHED0();
    if ((wid >> 1) == p) {      // waves whose 64 M-rows live in this pass
      const int b = wid & 1;
#pragma unroll
      for (int mi = 0; mi < 4; ++mi)
#pragma unroll
        for (int kf = 0; kf < 8; ++kf)
          a[mi][kf] = *(const bf16x8*)&lds[b][(kf >> 1) * 4096 + (mi * 16 + l15) * 64
              + ((((kf & 1) * 4 + (lane >> 4)) ^ l7) * 8)];
    }
    LGKM0(); BARR();            // reads done before next pass / B overwrites
  }

  bf16x8 bbA[8], bbB[8];        // double-buffered B fragment sets

  // ---- B tiles: dbuf; stage next, GATE(8), BARR, pipelined strips, BARR
  STGB(0, 0);
  for (int bt = 0; bt < NTILES - 1; ++bt) {
    STGB((bt + 1) & 1, bt + 1);
    GATE(8); BARR(); SCHED0();
    TILE(bt & 1);
    BARR();
  }
  GATE(0); BARR(); SCHED0();
  TILE((NTILES - 1) & 1);

  // reduce over the 16 column-lanes, one atomic per output row
#pragma unroll
  for (int mi = 0; mi < 4; ++mi)
#pragma unroll
    for (int ee = 0; ee < 4; ++ee) {
      float v = run[mi][ee];
      v = fmaxf(v, __shfl_xor(v, 1));
      v = fmaxf(v, __shfl_xor(v, 2));
      v = fmaxf(v, __shfl_xor(v, 4));
      v = fmaxf(v, __shfl_xor(v, 8));
      if (l15 == 0)
        atomicMaxFloat(&out[bm * BMT + wid * 64 + mi * 16 + (lane >> 4) * 4 + ee], v);
    }
}

extern "C" void kernel_launch(void* const* d_in, const int* in_sizes, int n_in,
                              void* d_out, int out_size, void* d_ws, size_t ws_size,
                              hipStream_t stream) {
  const float* refs = (const float*)d_in[0];
  const float* img  = (const float*)d_in[1];
  float* out = (float*)d_out;

  unsigned short* Rb = (unsigned short*)d_ws;                 // 131072*256 bf16 = 64MB
  unsigned short* Qb = Rb + (size_t)NREF * KD;                // 4096*256 bf16 = 2MB

  hipLaunchKernelGGL(norm_kernel, dim3(NNW * HN + HN), dim3(256), 0, stream,
                     refs, img, Rb, Qb, out);
  hipLaunchKernelGGL(simmax_kernel, dim3(NCHV * (HW / BMT)), dim3(256), 0, stream,
                     Qb, Rb, out);
}